// Round 7
// baseline (160.118 us; speedup 1.0000x reference)
//
#include <hip/hip_runtime.h>
#include <cstdint>
#include <cstddef>

// Outputs concat (f32): out(8,1024,256) qh(8,8,1024,32) kh(8,8,1024,32)
//                       v_img(8,256,32,32) atten(8,8,1024,1024)
#define OFF_OUT   0
#define OFF_QH    2097152
#define OFF_KH    4194304
#define OFF_VIMG  6291456
#define OFF_ATT   8388608

// ws layout (4-byte units)
#define WS_MQ   0        // 8*8*1024 u32
#define WS_MK   65536
#define WS_TBL  131072   // 1024*128*2 f32 (cos,sin interleaved)
#define WS_KVP  393216   // 64 bh * 4 seg * 32*32 f32 partial kv
#define WS_KMP  655360   // 64 bh * 4 seg * 32 f32 partial k-bit counts

typedef float f32x4 __attribute__((ext_vector_type(4)));

__device__ __forceinline__ unsigned spread2(unsigned v) {
    v = (v | (v << 8)) & 0x00FF00FFu;
    v = (v | (v << 4)) & 0x0F0F0F0Fu;
    v = (v | (v << 2)) & 0x33333333u;
    v = (v | (v << 1)) & 0x55555555u;
    return v;
}

// ---- fused GEMM+BN+LIF+pack, low-LDS-traffic structure ----
// Block tile: 8 n (wave = n) x 8 b x 128 c (lane = 2 c). 512 thr.
// x: wave-private LDS rows, broadcast ds_reads (no barrier for x).
// W: [32k][128c] LDS panels, contiguous b64 reads, dbuf, 1 barrier/panel.
__device__ __forceinline__ void gemm_lif_512(
    const float* __restrict__ x, const float* __restrict__ Wqk,
    const float* __restrict__ bqk, const float* __restrict__ gamma,
    const float* __restrict__ beta, unsigned* __restrict__ mq,
    unsigned* __restrict__ mk, float* pool,
    int blk_n, int blk_c, int t)
{
    const int w = t >> 6, lane = t & 63;
    const int n0 = blk_n * 8, c0 = blk_c * 128;
    const int n = n0 + w;
    // staging sources
    const float* gw = Wqk + (size_t)(t >> 5) * 512 + c0 + (t & 31) * 4;
    const float* gx = x + ((size_t)(lane >> 3) * 1024 + n) * 256 + (lane & 7) * 4;
    // LDS: W [2][32][128] at pool[0..8192); x [2][8w][8b][36] at pool[8192..12800)
    float* wd_base = pool + (t >> 5) * 128 + (t & 31) * 4;
    float* xs_w    = pool + 8192 + w * 288 + (lane >> 3) * 36 + (lane & 7) * 4;
    const float* xs_rd = pool + 8192 + w * 288;

    float acc[8][2];
    #pragma unroll
    for (int b = 0; b < 8; ++b) { acc[b][0] = 0.f; acc[b][1] = 0.f; }

    // prologue: stage panel 0, prefetch panel 1
    {
        f32x4 wA = *(const f32x4*)(gw);
        f32x4 wB = *(const f32x4*)(gw + (size_t)16 * 512);
        f32x4 xr = *(const f32x4*)(gx);
        *(f32x4*)(wd_base) = wA;
        *(f32x4*)(wd_base + 2048) = wB;
        *(f32x4*)(xs_w) = xr;
    }
    f32x4 wA_n = *(const f32x4*)(gw + (size_t)32 * 512);
    f32x4 wB_n = *(const f32x4*)(gw + (size_t)48 * 512);
    f32x4 xr_n = *(const f32x4*)(gx + 32);

    for (int p = 0; p < 8; ++p) {
        __syncthreads();
        if (p < 7) {
            int nb = (p + 1) & 1;
            *(f32x4*)(wd_base + nb * 4096)        = wA_n;
            *(f32x4*)(wd_base + nb * 4096 + 2048) = wB_n;
            *(f32x4*)(xs_w + nb * 2304)           = xr_n;
            if (p < 6) {
                int ko = (p + 2) * 32;
                wA_n = *(const f32x4*)(gw + (size_t)ko * 512);
                wB_n = *(const f32x4*)(gw + (size_t)(ko + 16) * 512);
                xr_n = *(const f32x4*)(gx + ko);
            }
        }
        const float* wsp = pool + (p & 1) * 4096;
        const float* xsp = xs_rd + (p & 1) * 2304;
        #pragma unroll
        for (int kk4 = 0; kk4 < 8; ++kk4) {
            f32x4 xv[8];
            #pragma unroll
            for (int b = 0; b < 8; ++b)
                xv[b] = *(const f32x4*)(xsp + b * 36 + kk4 * 4);  // broadcast
            #pragma unroll
            for (int j = 0; j < 4; ++j) {
                float2 w2 = *(const float2*)(wsp + (kk4 * 4 + j) * 128 + lane * 2);
                #pragma unroll
                for (int b = 0; b < 8; ++b) {
                    acc[b][0] = fmaf(xv[b][j], w2.x, acc[b][0]);
                    acc[b][1] = fmaf(xv[b][j], w2.y, acc[b][1]);
                }
            }
        }
    }

    // BN + LIF (serial over b) + ballot bit-pack
    float g = gamma[n], be = beta[n];
    float2 bq = *(const float2*)&bqk[c0 + lane * 2];
    unsigned* dst = (blk_c < 2) ? mq : mk;
    int hbase = (blk_c & 1) * 4;
    float v0 = 0.f, v1 = 0.f;
    #pragma unroll
    for (int b = 0; b < 8; ++b) {
        float a0 = (acc[b][0] + bq.x) * g + be;
        float a1 = (acc[b][1] + bq.y) * g + be;
        v0 = v0 + (a0 - v0) * 0.5f;
        v1 = v1 + (a1 - v1) * 0.5f;
        bool s0 = (v0 >= 1.f), s1 = (v1 >= 1.f);
        v0 = s0 ? 0.f : v0; v1 = s1 ? 0.f : v1;
        unsigned long long m0 = __ballot(s0 ? 1 : 0);
        unsigned long long m1 = __ballot(s1 ? 1 : 0);
        if (lane < 4) {
            unsigned a = (unsigned)(m0 >> (lane * 16)) & 0xFFFFu;
            unsigned c = (unsigned)(m1 >> (lane * 16)) & 0xFFFFu;
            dst[b * 8192 + (hbase + lane) * 1024 + n] = spread2(a) | (spread2(c) << 1);
        }
    }
}

// =====================================================================
// Phase A (512 thr, 1536 blocks):
//  [0,256)    : GEMM blk_c in {2,3}  -> mk
//  [256,1280) : vimg transpose, 2 tiles/block
//  [1280,1536): rope table
// =====================================================================
__global__ __launch_bounds__(512) void phaseA_kernel(
    const float* __restrict__ x, const float* __restrict__ Wqk,
    const float* __restrict__ bqk, const float* __restrict__ gamma,
    const float* __restrict__ beta, unsigned* __restrict__ mq,
    unsigned* __restrict__ mk, float* __restrict__ vimg,
    float* __restrict__ tbl)
{
    __shared__ float smem[12800];
    int t = threadIdx.x;
    int blk = blockIdx.x;
    if (blk < 256) {
        gemm_lif_512(x, Wqk, bqk, gamma, beta, mq, mk, smem,
                     blk >> 1, 2 + (blk & 1), t);
        return;
    }
    if (blk >= 1280) {                     // ---- rope table ----
        int id = (blk - 1280) * 512 + t;   // 131072 total
        int j = id & 127, n = id >> 7;
        int i = (j < 64) ? j : j - 64;
        float th = powf(10000.0f, -(float)i * (1.0f / 64.0f));
        float pos = (float)((j < 64) ? (n >> 5) : (n & 31));
        float ang = pos * th;
        tbl[n * 256 + j * 2]     = cosf(ang);
        tbl[n * 256 + j * 2 + 1] = sinf(ang);
        return;
    }
    // ---- vimg transpose ----
    int tile = (blk - 256) * 2 + (t >> 8);
    int st = t & 255;
    float* s = smem + (t >> 8) * 1056; // [32][33]
    int b = tile >> 8, ti = tile & 255;
    int p0 = (ti >> 3) * 32, c0 = (ti & 7) * 32;
    int row = st >> 3, c4 = (st & 7) * 4;
    const float4 vl = *(const float4*)&x[(b * 1024 + p0 + row) * 256 + c0 + c4];
    s[row * 33 + c4 + 0] = vl.x; s[row * 33 + c4 + 1] = vl.y;
    s[row * 33 + c4 + 2] = vl.z; s[row * 33 + c4 + 3] = vl.w;
    __syncthreads();
    int cc = st >> 3, p4 = (st & 7) * 4;
    f32x4 o;
    o.x = s[(p4 + 0) * 33 + cc]; o.y = s[(p4 + 1) * 33 + cc];
    o.z = s[(p4 + 2) * 33 + cc]; o.w = s[(p4 + 3) * 33 + cc];
    *(f32x4*)&vimg[(b * 256 + c0 + cc) * 1024 + p0 + p4] = o;
}

// =====================================================================
// Phase B (512 thr, 384 blocks):
//  [0,256)   : GEMM blk_c in {0,1}  -> mq
//  [256,384) : kv partials + k-bit counts, 2 units/block
// =====================================================================
__global__ __launch_bounds__(512) void phaseB_kernel(
    const float* __restrict__ x, const float* __restrict__ Wqk,
    const float* __restrict__ bqk, const float* __restrict__ gamma,
    const float* __restrict__ beta, unsigned* __restrict__ mq,
    unsigned* __restrict__ mk, const float* __restrict__ tbl,
    float* __restrict__ kvp, float* __restrict__ kmp)
{
    __shared__ float smem[12800];
    int t = threadIdx.x;
    int blk = blockIdx.x;
    if (blk < 256) {
        gemm_lif_512(x, Wqk, bqk, gamma, beta, mq, mk, smem,
                     blk >> 1, blk & 1, t);
        return;
    }
    // ---- kv partials: 2 independent 256-thr units ----
    int ks2 = t >> 8, tl = t & 255;
    int unit = (blk - 256) * 2 + ks2;      // 0..255
    int bh = unit >> 2, seg = unit & 3;
    int b = bh >> 3, h = bh & 7;
    int n0 = seg * 256;
    float* kr   = smem + ks2 * 4800;       // [64][36]
    float* vhs  = kr + 2304;               // [64][33]
    float* part = kr + 4416;               // [8][32]
    int d = tl & 31, ch = tl >> 5;
    int sc = 0;
    for (int i = 0; i < 32; ++i)
        sc += (mk[bh * 1024 + n0 + ch * 32 + i] >> d) & 1u;
    part[ch * 32 + d] = (float)sc;
    __syncthreads();
    if (tl < 32) {
        float cs = 0.f;
        #pragma unroll
        for (int j = 0; j < 8; ++j) cs += part[j * 32 + tl];
        kmp[bh * 128 + seg * 32 + tl] = cs;
    }
    float a0 = 0, a1 = 0, a2 = 0, a3 = 0;
    int e = tl & 31, db = (tl >> 5) * 4;
    for (int c0 = n0; c0 < n0 + 256; c0 += 64) {
        __syncthreads();
        #pragma unroll
        for (int i = 0; i < 8; ++i) {
            int f = tl + i * 256;
            int nn = f >> 5, dd = f & 31;
            int n = c0 + nn;
            unsigned w = mk[bh * 1024 + n];
            float kd = 1.0f + (float)((w >> dd) & 1u);
            float ko = 1.0f + (float)((w >> (dd ^ 1)) & 1u);
            const float* cp = tbl + n * 256 + h * 32 + (dd & ~1);
            float cc2 = cp[0], ss2 = cp[1];
            kr[nn * 36 + dd] = (dd & 1) ? (ss2 * ko + cc2 * kd) : (cc2 * kd - ss2 * ko);
            vhs[nn * 33 + dd] = x[(b * 1024 + n) * 256 + h * 32 + dd];
        }
        __syncthreads();
        #pragma unroll 8
        for (int nn = 0; nn < 64; ++nn) {
            float ve = vhs[nn * 33 + e];
            float4 kk = *(const float4*)&kr[nn * 36 + db];
            a0 = fmaf(kk.x, ve, a0); a1 = fmaf(kk.y, ve, a1);
            a2 = fmaf(kk.z, ve, a2); a3 = fmaf(kk.w, ve, a3);
        }
    }
    float* dst = kvp + bh * 4096 + seg * 1024;
    dst[(db + 0) * 32 + e] = a0;
    dst[(db + 1) * 32 + e] = a1;
    dst[(db + 2) * 32 + e] = a2;
    dst[(db + 3) * 32 + e] = a3;
}

// =====================================================================
// Phase C (256 thr, 2560 blocks): all heavy writes (plain stores)
//  [0,512)    : out = q_rope@kv * z + lepe
//  [512,2560) : atten + qh/kh regen
// =====================================================================
__global__ __launch_bounds__(256) void phaseC_kernel(
    const unsigned* __restrict__ mq, const unsigned* __restrict__ mk,
    const float* __restrict__ x, const float* __restrict__ tbl,
    const float* __restrict__ kvp, const float* __restrict__ kmp,
    const float* __restrict__ lw, const float* __restrict__ lb,
    float* __restrict__ outbase)
{
    int t = threadIdx.x;
    if (blockIdx.x >= 512) {               // ---- atten + qh/kh ----
        int blk = blockIdx.x - 512;
        int bh = blk >> 5;
        int tile = blk & 31;
        float* qh = outbase + OFF_QH;
        float* kh = outbase + OFF_KH;
        float* att = outbase + OFF_ATT;
        {
            int row = tile * 32 + (t >> 3);
            int d0 = (t & 7) * 4;
            unsigned wq = mq[bh * 1024 + row], wk = mk[bh * 1024 + row];
            f32x4 a, bb;
            a.x = 1.f + (float)((wq >> (d0 + 0)) & 1u);
            a.y = 1.f + (float)((wq >> (d0 + 1)) & 1u);
            a.z = 1.f + (float)((wq >> (d0 + 2)) & 1u);
            a.w = 1.f + (float)((wq >> (d0 + 3)) & 1u);
            bb.x = 1.f + (float)((wk >> (d0 + 0)) & 1u);
            bb.y = 1.f + (float)((wk >> (d0 + 1)) & 1u);
            bb.z = 1.f + (float)((wk >> (d0 + 2)) & 1u);
            bb.w = 1.f + (float)((wk >> (d0 + 3)) & 1u);
            *(f32x4*)&qh[((bh * 1024 + row) << 5) + d0] = a;
            *(f32x4*)&kh[((bh * 1024 + row) << 5) + d0] = bb;
        }
        uint4 mm = ((const uint4*)(mk + bh * 1024))[t];
        float4 rr;
        rr.x = (float)__popc(mm.x); rr.y = (float)__popc(mm.y);
        rr.z = (float)__popc(mm.z); rr.w = (float)__popc(mm.w);
        float* base = att + ((size_t)bh * 1024 + (size_t)tile * 32) * 1024;
        const unsigned* mqrow = mq + bh * 1024 + tile * 32;
        for (int row = 0; row < 32; ++row) {
            unsigned mqw = mqrow[row];
            float rq = 32.0f + (float)__popc(mqw);
            f32x4 o;
            o.x = rq + rr.x + (float)__popc(mqw & mm.x);
            o.y = rq + rr.y + (float)__popc(mqw & mm.y);
            o.z = rq + rr.z + (float)__popc(mqw & mm.z);
            o.w = rq + rr.w + (float)__popc(mqw & mm.w);
            ((f32x4*)(base + (size_t)row * 1024))[t] = o;
        }
        return;
    }
    // ---- out ----
    int bi = blockIdx.x;
    int bh = bi >> 3, sub = bi & 7;
    int pseg = sub >> 1, half = sub & 1;
    int b = bh >> 3, h = bh & 7;
    bool hy = (h < 4);
    int e = t & 31, p_l = t >> 5;
    int p = pseg * 8 + p_l;
    int q0 = half * 16;
    float* out = outbase + OFF_OUT;

    __shared__ float kvs[32][32];
    __shared__ float kmf[32];
    __shared__ float zs[128];
    const float inv = 1.0f / 1024.0f;
    #pragma unroll
    for (int i = 0; i < 4; ++i) {
        int f = t + i * 256;
        const float* kp = kvp + bh * 4096 + f;
        kvs[f >> 5][f & 31] = (kp[0] + kp[1024] + kp[2048] + kp[3072]) * inv;
    }
    if (t < 32) {
        const float* mp = kmp + bh * 128 + t;
        kmf[t] = 1.0f + (mp[0] + mp[32] + mp[64] + mp[96]) * inv;
    }
    __syncthreads();
    float S = 0.f;
    #pragma unroll
    for (int dd = 0; dd < 32; ++dd) S += kmf[dd];
    if (t < 128) {
        int pl2 = t >> 4, iq = t & 15;
        int pp = pseg * 8 + pl2, qq = q0 + iq;
        int n = hy ? (pp * 32 + qq) : (qq * 32 + pp);
        unsigned w = mq[bh * 1024 + n];
        float acc = S;
        #pragma unroll
        for (int dd = 0; dd < 32; ++dd)
            acc += (float)((w >> dd) & 1u) * kmf[dd];
        zs[t] = 1.0f / (acc + 1e-6f);
    }
    int n_ref = hy ? (p * 32) : p;
    const float* cp = tbl + n_ref * 256 + h * 32;
    float E[16], O[16], B = 0.f;
    #pragma unroll
    for (int j = 0; j < 16; ++j) {
        float c2 = cp[2 * j], s2 = cp[2 * j + 1];
        float K0 = kvs[2 * j][e], K1 = kvs[2 * j + 1][e];
        E[j] = c2 * K0 + s2 * K1;
        O[j] = c2 * K1 - s2 * K0;
        B += E[j] + O[j];
    }
    __syncthreads();
    int c = h * 32 + e;
    float w9[9];
    #pragma unroll
    for (int j = 0; j < 9; ++j) w9[j] = lw[c * 9 + j];
    float lbv = lb[c];
    const float* xb = x + (size_t)b * 262144 + c;
    auto ld = [&](int yy, int xx) -> float {
        if ((unsigned)yy > 31u || (unsigned)xx > 31u) return 0.f;
        return xb[(yy * 32 + xx) * 256];
    };
    if (hy) {
        int y = p;
        float Wm0 = ld(y - 1, q0 - 1), Wm1 = ld(y, q0 - 1), Wm2 = ld(y + 1, q0 - 1);
        float Wc0 = ld(y - 1, q0),     Wc1 = ld(y, q0),     Wc2 = ld(y + 1, q0);
        #pragma unroll 4
        for (int i = 0; i < 16; ++i) {
            int m = q0 + i;
            float Wp0 = ld(y - 1, m + 1), Wp1 = ld(y, m + 1), Wp2 = ld(y + 1, m + 1);
            int n = y * 32 + m;
            unsigned w = mq[bh * 1024 + n];
            float o = B;
            #pragma unroll
            for (int j = 0; j < 16; ++j) {
                o += (float)((w >> (2 * j)) & 1u) * E[j];
                o += (float)((w >> (2 * j + 1)) & 1u) * O[j];
            }
            o *= zs[p_l * 16 + i];
            float l = lbv;
            l = fmaf(w9[0], Wm0, l); l = fmaf(w9[1], Wc0, l); l = fmaf(w9[2], Wp0, l);
            l = fmaf(w9[3], Wm1, l); l = fmaf(w9[4], Wc1, l); l = fmaf(w9[5], Wp1, l);
            l = fmaf(w9[6], Wm2, l); l = fmaf(w9[7], Wc2, l); l = fmaf(w9[8], Wp2, l);
            out[((b * 1024 + n) << 8) + c] = o + l;
            Wm0 = Wc0; Wm1 = Wc1; Wm2 = Wc2;
            Wc0 = Wp0; Wc1 = Wp1; Wc2 = Wp2;
        }
    } else {
        int xx0 = p;
        float Wm0 = ld(q0 - 1, xx0 - 1), Wm1 = ld(q0 - 1, xx0), Wm2 = ld(q0 - 1, xx0 + 1);
        float Wc0 = ld(q0, xx0 - 1),     Wc1 = ld(q0, xx0),     Wc2 = ld(q0, xx0 + 1);
        #pragma unroll 4
        for (int i = 0; i < 16; ++i) {
            int m = q0 + i;
            float Wp0 = ld(m + 1, xx0 - 1), Wp1 = ld(m + 1, xx0), Wp2 = ld(m + 1, xx0 + 1);
            int n = m * 32 + xx0;
            unsigned w = mq[bh * 1024 + n];
            float o = B;
            #pragma unroll
            for (int j = 0; j < 16; ++j) {
                o += (float)((w >> (2 * j)) & 1u) * E[j];
                o += (float)((w >> (2 * j + 1)) & 1u) * O[j];
            }
            o *= zs[p_l * 16 + i];
            float l = lbv;
            l = fmaf(w9[0], Wm0, l); l = fmaf(w9[1], Wm1, l); l = fmaf(w9[2], Wm2, l);
            l = fmaf(w9[3], Wc0, l); l = fmaf(w9[4], Wc1, l); l = fmaf(w9[5], Wc2, l);
            l = fmaf(w9[6], Wp0, l); l = fmaf(w9[7], Wp1, l); l = fmaf(w9[8], Wp2, l);
            out[((b * 1024 + n) << 8) + c] = o + l;
            Wm0 = Wc0; Wm1 = Wc1; Wm2 = Wc2;
            Wc0 = Wp0; Wc1 = Wp1; Wc2 = Wp2;
        }
    }
}

extern "C" void kernel_launch(void* const* d_in, const int* in_sizes, int n_in,
                              void* d_out, int out_size, void* d_ws, size_t ws_size,
                              hipStream_t stream)
{
    const float* x     = (const float*)d_in[0];
    const float* Wqk   = (const float*)d_in[1];
    const float* bqk   = (const float*)d_in[2];
    const float* gamma = (const float*)d_in[3];
    const float* beta  = (const float*)d_in[4];
    const float* lw    = (const float*)d_in[5];
    const float* lb    = (const float*)d_in[6];
    float* out = (float*)d_out;
    unsigned* ws = (unsigned*)d_ws;
    unsigned* mq = ws + WS_MQ;
    unsigned* mk = ws + WS_MK;
    float* tbl  = (float*)(ws + WS_TBL);
    float* kvp  = (float*)(ws + WS_KVP);
    float* kmp  = (float*)(ws + WS_KMP);

    hipLaunchKernelGGL(phaseA_kernel, dim3(1536), dim3(512), 0, stream,
                       x, Wqk, bqk, gamma, beta, mq, mk, out + OFF_VIMG, tbl);
    hipLaunchKernelGGL(phaseB_kernel, dim3(384), dim3(512), 0, stream,
                       x, Wqk, bqk, gamma, beta, mq, mk, tbl, kvp, kmp);
    hipLaunchKernelGGL(phaseC_kernel, dim3(2560), dim3(256), 0, stream,
                       mq, mk, x, tbl, kvp, kmp, lw, lb, out);
}